// Round 2
// baseline (1398.536 us; speedup 1.0000x reference)
//
#include <hip/hip_runtime.h>
#include <stdint.h>

#define B_   4096
#define T_   26
#define NC_  97
#define PROBS_SZ ((size_t)B_*T_*NC_)   // 10,330,112

using frag8 = __attribute__((ext_vector_type(8))) short;   // 8 bf16
using f32x4 = __attribute__((ext_vector_type(4))) float;   // MFMA acc

__device__ inline unsigned short f2bf(float f) {
  unsigned u = __float_as_uint(f);
  return (unsigned short)((u + 0x7fffu + ((u >> 16) & 1u)) >> 16); // RNE
}
__device__ inline float bf2f(unsigned short h) {
  return __uint_as_float(((unsigned)h) << 16);
}
__device__ inline float sigf(float x) { return 1.f / (1.f + __expf(-x)); }
__device__ inline float tanh_(float x) {
  float e = __expf(2.f * x);
  return 1.f - 2.f / (e + 1.f);   // saturates correctly at +/-1
}

__device__ inline void gld16(const void* g, void* l) {
  __builtin_amdgcn_global_load_lds(
      (const __attribute__((address_space(1))) void*)g,
      (__attribute__((address_space(3))) void*)l, 16, 0, 0);
}

// permuted gate-column p -> original gate row g:
// p = tile*128 + wn*64 + gate*16 + ul ; unit j = tile*32 + wn*16 + ul ; g = gate*512 + j
__device__ inline int perm_to_orig(int p) {
  int tile = p >> 7, wn = (p >> 6) & 1, gate = (p >> 4) & 3, ul = p & 15;
  return gate * 512 + tile * 32 + wn * 16 + ul;
}

// one BK=32 chunk of the 128x128 m97-style GEMM (256 threads)
__device__ inline void chunk(const unsigned short* __restrict__ Ab, size_t lda,
                             const unsigned short* __restrict__ Bb, size_t ldb,
                             unsigned short* As, unsigned short* Bs, f32x4 acc[4][4]) {
  const int tid = threadIdx.x;
  const int r4 = tid >> 2, c8 = (tid & 3) * 8;
  const int lane = tid & 63, w = tid >> 6;
  const int wm = w >> 1, wn = w & 1, l15 = lane & 15, quad = lane >> 4;
  gld16(Ab + (size_t)r4 * lda + c8,        (char*)As + tid * 16);
  gld16(Ab + (size_t)(r4 + 64) * lda + c8, (char*)As + 4096 + tid * 16);
  gld16(Bb + (size_t)r4 * ldb + c8,        (char*)Bs + tid * 16);
  gld16(Bb + (size_t)(r4 + 64) * ldb + c8, (char*)Bs + 4096 + tid * 16);
  __syncthreads();
  frag8 a[4], b[4];
#pragma unroll
  for (int i = 0; i < 4; i++)
    a[i] = *(const frag8*)(As + (wm * 64 + i * 16 + l15) * 32 + quad * 8);
#pragma unroll
  for (int i = 0; i < 4; i++)
    b[i] = *(const frag8*)(Bs + (wn * 64 + i * 16 + l15) * 32 + quad * 8);
#pragma unroll
  for (int i = 0; i < 4; i++)
#pragma unroll
    for (int j = 0; j < 4; j++)
      acc[i][j] = __builtin_amdgcn_mfma_f32_16x16x32_bf16(a[i], b[j], acc[i][j], 0, 0, 0);
  __syncthreads();
}

// ---- prep ----
__global__ void k_cast_x(const float* __restrict__ x, unsigned short* __restrict__ o) {
  long i = (long)blockIdx.x * 256 + threadIdx.x;  // one thread = 8 elements
  const float4* p = (const float4*)x;
  float4 a = p[i * 2], b = p[i * 2 + 1];
  frag8 r;
  r[0] = (short)f2bf(a.x); r[1] = (short)f2bf(a.y);
  r[2] = (short)f2bf(a.z); r[3] = (short)f2bf(a.w);
  r[4] = (short)f2bf(b.x); r[5] = (short)f2bf(b.y);
  r[6] = (short)f2bf(b.z); r[7] = (short)f2bf(b.w);
  *(frag8*)(o + i * 8) = r;
}

// wcomb[p][k] = k<512 ? W_ih[g][k] : W_hh[g][k-512]   (g = perm_to_orig(p))
// wgenp[n][k] = n<97 ? W_gen[n][k] : 0
__global__ void k_prep_w(const float* __restrict__ Wih, const float* __restrict__ Whh,
                         const float* __restrict__ Wgen,
                         unsigned short* __restrict__ wcomb,
                         unsigned short* __restrict__ wgenp) {
  int gid = blockIdx.x * 256 + threadIdx.x;  // 2,162,688 total
  if (gid < 2097152) {
    int p = gid >> 10, k = gid & 1023;
    int g = perm_to_orig(p);
    float v = (k < 512) ? Wih[(size_t)g * 768 + k] : Whh[(size_t)g * 512 + (k - 512)];
    wcomb[gid] = f2bf(v);
  } else {
    int lid = gid - 2097152;        // < 65,536
    int n = lid >> 9, k = lid & 511;
    wgenp[lid] = (n < NC_) ? f2bf(Wgen[(size_t)n * 512 + k]) : 0;
  }
}

__global__ void k_wembT(const float* __restrict__ Wih, float* __restrict__ wt) {
  int gid = blockIdx.x * 256 + threadIdx.x;  // 524,288
  int e = gid >> 11, p = gid & 2047;
  wt[gid] = Wih[(size_t)perm_to_orig(p) * 768 + 512 + e];
}

// tc[cls][p] = b_ih[g] + b_hh[g] + emb[cls]·W_ih[g][512:768]
__global__ void k_tc(const float* __restrict__ emb, const float* __restrict__ wt,
                     const float* __restrict__ bih, const float* __restrict__ bhh,
                     float* __restrict__ tc) {
  int gid = blockIdx.x * 256 + threadIdx.x;  // 200,704
  int cls = gid >> 11, p = gid & 2047;
  int g = perm_to_orig(p);
  float s = bih[g] + bhh[g];
  const float* er = emb + (size_t)cls * 256;
#pragma unroll 4
  for (int e = 0; e < 256; e++) s += er[e] * wt[(size_t)e * 2048 + p];
  tc[gid] = s;
}

// ---- fused LSTM step: gates = [x_t ; h_{t-1}] @ wcomb^T + tc[text] ----
__global__ __launch_bounds__(256, 2) void k_step(const unsigned short* __restrict__ X,
                                                 const unsigned short* __restrict__ hs,
                                                 const unsigned short* __restrict__ W,
                                                 const float* __restrict__ tc,
                                                 const int* __restrict__ text,
                                                 float* __restrict__ cbuf,
                                                 unsigned short* hsw,
                                                 float* __restrict__ outH, int t) {
  __shared__ unsigned short As[128 * 32], Bs[128 * 32];
  f32x4 acc[4][4];
#pragma unroll
  for (int i = 0; i < 4; i++)
#pragma unroll
    for (int j = 0; j < 4; j++) acc[i][j] = (f32x4){0.f, 0.f, 0.f, 0.f};
  const int n0 = blockIdx.x * 128, m0 = blockIdx.y * 128;
  const unsigned short* A0 = X + (size_t)t * 512 + (size_t)m0 * 13312;
  const unsigned short* A1 = hs + (size_t)(t > 0 ? t - 1 : 0) * 512 + (size_t)m0 * 13312;
  const unsigned short* Bb = W + (size_t)n0 * 1024;
  const int Keff = t ? 1024 : 512;   // h0 = 0: skip the h half at t=0
  for (int k0 = 0; k0 < Keff; k0 += 32) {
    const unsigned short* Ab = (k0 < 512) ? A0 + k0 : A1 + (k0 - 512);
    chunk(Ab, 13312, Bb + k0, 1024, As, Bs, acc);
  }
  const int tid = threadIdx.x, lane = tid & 63, w = tid >> 6;
  const int wm = w >> 1, wn = w & 1, l15 = lane & 15, quad = lane >> 4;
  const int j = (n0 >> 2) + wn * 16 + l15;      // hidden unit owned by this lane
  const int colb = n0 + wn * 64 + l15;          // base permuted column (gate 0)
#pragma unroll
  for (int fr = 0; fr < 4; fr++) {
#pragma unroll
    for (int reg = 0; reg < 4; reg++) {
      int r = m0 + wm * 64 + fr * 16 + quad * 4 + reg;  // batch row
      int cls = text[r * 26 + t];
      const float* tcr = tc + (size_t)cls * 2048 + colb;
      float p0 = acc[fr][0][reg] + tcr[0];
      float p1 = acc[fr][1][reg] + tcr[16];
      float p2 = acc[fr][2][reg] + tcr[32];
      float p3 = acc[fr][3][reg] + tcr[48];
      float cp = t ? cbuf[(size_t)r * 512 + j] : 0.f;
      float ii = sigf(p0), ff = sigf(p1), gg = tanh_(p2), oo = sigf(p3);
      float cn = ff * cp + ii * gg;
      float h = oo * tanh_(cn);
      cbuf[(size_t)r * 512 + j] = cn;
      hsw[((size_t)r * 26 + t) * 512 + j] = f2bf(h);
      outH[((size_t)r * 26 + t) * 512 + j] = h;
    }
  }
}

// ---- probs: out[m][c] = hs[m]·Wgen[c] + bg[c]  (N padded to 128) ----
__global__ __launch_bounds__(256, 2) void k_probs(const unsigned short* __restrict__ hs,
                                                  const unsigned short* __restrict__ Wg,
                                                  const float* __restrict__ bg,
                                                  float* __restrict__ out) {
  __shared__ unsigned short As[128 * 32], Bs[128 * 32];
  f32x4 acc[4][4];
#pragma unroll
  for (int i = 0; i < 4; i++)
#pragma unroll
    for (int j = 0; j < 4; j++) acc[i][j] = (f32x4){0.f, 0.f, 0.f, 0.f};
  const int m0 = blockIdx.x * 128;
  for (int k0 = 0; k0 < 512; k0 += 32)
    chunk(hs + (size_t)m0 * 512 + k0, 512, Wg + k0, 512, As, Bs, acc);
  const int tid = threadIdx.x, lane = tid & 63, w = tid >> 6;
  const int wm = w >> 1, wn = w & 1, l15 = lane & 15, quad = lane >> 4;
#pragma unroll
  for (int fr = 0; fr < 4; fr++) {
#pragma unroll
    for (int reg = 0; reg < 4; reg++) {
      int m = m0 + wm * 64 + fr * 16 + quad * 4 + reg;
#pragma unroll
      for (int fc = 0; fc < 4; fc++) {
        int col = wn * 64 + fc * 16 + l15;
        if (col < NC_) out[(size_t)m * NC_ + col] = acc[fr][fc][reg] + bg[col];
      }
    }
  }
}

extern "C" void kernel_launch(void* const* d_in, const int* in_sizes, int n_in,
                              void* d_out, int out_size, void* d_ws, size_t ws_size,
                              hipStream_t stream) {
  const float* batch_H = (const float*)d_in[0];
  const int*   text    = (const int*)d_in[1];
  const float* emb     = (const float*)d_in[2];
  const float* W_ih    = (const float*)d_in[3];
  const float* W_hh    = (const float*)d_in[4];
  const float* b_ih    = (const float*)d_in[5];
  const float* b_hh    = (const float*)d_in[6];
  const float* W_gen   = (const float*)d_in[7];
  const float* b_gen   = (const float*)d_in[8];
  float* out = (float*)d_out;
  char* ws = (char*)d_ws;

  // workspace carve (total 233,717,760 B ≈ 223 MiB)
  unsigned short* X     = (unsigned short*)(ws + 0);             // 109,051,904
  unsigned short* hs    = (unsigned short*)(ws + 109051904ULL);  // 109,051,904
  float*          cbuf  = (float*)(ws + 218103808ULL);           //   8,388,608
  unsigned short* wcomb = (unsigned short*)(ws + 226492416ULL);  //   4,194,304
  unsigned short* wgenp = (unsigned short*)(ws + 230686720ULL);  //     131,072
  float*          tc    = (float*)(ws + 230817792ULL);           //     802,816
  float*          wembT = (float*)(ws + 231620608ULL);           //   2,097,152

  k_cast_x<<<26624, 256, 0, stream>>>(batch_H, X);
  k_prep_w<<<8448, 256, 0, stream>>>(W_ih, W_hh, W_gen, wcomb, wgenp);
  k_wembT<<<2048, 256, 0, stream>>>(W_ih, wembT);
  k_tc<<<784, 256, 0, stream>>>(emb, wembT, b_ih, b_hh, tc);
  for (int t = 0; t < 26; t++)
    k_step<<<dim3(16, 32), 256, 0, stream>>>(X, hs, wcomb, tc, text, cbuf, hs,
                                             out + PROBS_SZ, t);
  k_probs<<<832, 256, 0, stream>>>(hs, wgenp, b_gen, out);
}